// Round 3
// baseline (418.889 us; speedup 1.0000x reference)
//
#include <hip/hip_runtime.h>

typedef __attribute__((ext_vector_type(8))) __bf16 bf16x8;
typedef __attribute__((ext_vector_type(4))) float f32x4;

#define GRID 1024
#define BLOCK 512
#define ITERS 8   // 4 batch rows per iter -> 32 rows per block

// swizzle for 128-col bf16 LDS tiles
__device__ __forceinline__ int swz(int row, int col) {
    return row * 128 + (col ^ ((row & 7) << 3));
}
// swizzle for 16-col bf16 LDS tiles
__device__ __forceinline__ int swz16(int row, int col) {
    return row * 16 + (col ^ ((row & 1) << 3));
}

// ws layout (bytes):
//   0      : W1 packed bf16 [128][16] (f=15 zeroed), swz16-swizzled
//   4096   : W2 bf16 [128][128] swz-swizzled    (col=out e, k=in d)
//   36864  : W3 bf16 [128][128] swz-swizzled
//   69632  : M  f32  [128][128]  M[d][f] = sum_e Ur[e][d]*Uq[e][f]
//   135168 : end

__global__ __launch_bounds__(128)
void pack_kernel(const float* __restrict__ W1, const float* __restrict__ W2,
                 const float* __restrict__ W3, const float* __restrict__ Uq,
                 const float* __restrict__ Ur, unsigned char* __restrict__ ws)
{
    __bf16* w1p = (__bf16*)ws;
    __bf16* w2p = (__bf16*)(ws + 4096);
    __bf16* w3p = (__bf16*)(ws + 36864);
    float*  Mp  = (float*)(ws + 69632);
    const int d = blockIdx.x;   // 0..127 (row / out-dim)
    const int t = threadIdx.x;  // 0..127
    if (t < 16) w1p[swz16(d, t)] = (__bf16)((t < 15) ? W1[d * 15 + t] : 0.f);
    w2p[swz(d, t)] = (__bf16)W2[d * 128 + t];
    w3p[swz(d, t)] = (__bf16)W3[d * 128 + t];
    float acc = 0.f;
    for (int e = 0; e < 128; ++e)
        acc = fmaf(Ur[e * 128 + d], Uq[e * 128 + t], acc);
    Mp[d * 128 + t] = acc;
}

__global__ __launch_bounds__(BLOCK, 2)
void fused_attn_kernel(const float* __restrict__ obs,
                       const float* __restrict__ b1g, const float* __restrict__ b2g,
                       const float* __restrict__ b3g,
                       const unsigned char* __restrict__ ws,
                       float* __restrict__ out)
{
    const __bf16* gW1 = (const __bf16*)ws;
    const __bf16* gW2 = (const __bf16*)(ws + 4096);
    const __bf16* gW3 = (const __bf16*)(ws + 36864);
    const float*  gM  = (const float*)(ws + 69632);

    __shared__ __align__(16) __bf16 sW1[128 * 16];
    __shared__ __align__(16) __bf16 sW2[128 * 128];
    __shared__ __align__(16) __bf16 sW3[128 * 128];
    __shared__ __align__(16) __bf16 sH [128 * 128];   // h1 then h2 (wave-private rows)
    __shared__ __align__(16) __bf16 sXr[128 * 128];   // x_real
    __shared__ float sMask[128];
    __shared__ float sB1[128], sB2[128], sB3[128];
    __shared__ float sQp[8 * 128];                    // per-wave colsum partials
    __shared__ float sDp[8];                          // per-wave mask-sum partials
    __shared__ __align__(16) float sVp[2 * 4 * 128];  // v partials per wc half
    __shared__ float sWgt[128];

    const int tid  = threadIdx.x;
    const int lane = tid & 63;
    const int wv   = tid >> 6;        // 0..7 ; owns tile rows [wv*16, wv*16+16)
    const int l15  = lane & 15;
    const int kh   = lane >> 4;       // 0..3
    const int rowbase = wv * 16;

    // ---- stage packed weights (already swizzled in ws) + biases ----
    for (int i = tid * 8; i < 128 * 16; i += BLOCK * 8)
        *(bf16x8*)&sW1[i] = *(const bf16x8*)&gW1[i];
    for (int i = tid * 8; i < 128 * 128; i += BLOCK * 8) {
        *(bf16x8*)&sW2[i] = *(const bf16x8*)&gW2[i];
        *(bf16x8*)&sW3[i] = *(const bf16x8*)&gW3[i];
    }
    if (tid < 128) { sB1[tid] = b1g[tid]; sB2[tid] = b2g[tid]; sB3[tid] = b3g[tid]; }
    __syncthreads();

    for (int g = 0; g < ITERS; ++g) {
        const int row0  = blockIdx.x * (4 * ITERS) + g * 4;
        const int rb    = row0 + (wv >> 1);     // this wave's batch row
        const int nbase = (wv & 1) * 16;        // its 16 objects: nbase..nbase+15

        bf16x8 zf;
        #pragma unroll
        for (int j = 0; j < 8; ++j) zf[j] = (__bf16)0.f;

        float mk[4];   // mask for this lane's C-rows (tile-local kh*4+r)

        // ============ L1 (wave-local, feats direct from global) ============
        {
            // A-frag: row = nbase+l15 (object), k = (kh&1)*8 + j ; kh>=2 -> zero
            const float* src = &obs[(size_t)rb * 576 + 32 + (size_t)(nbase + l15) * 16 + (kh & 1) * 8];
            f32x4 u0 = *(const f32x4*)src;
            f32x4 u1 = *(const f32x4*)(src + 4);
            float maskv = 0.f;
            if (kh & 1) { maskv = u1.w; u1.w = 0.f; }   // feature 15 = mask
            bf16x8 afr = zf;
            if (kh < 2) {
                afr[0] = (__bf16)u0.x; afr[1] = (__bf16)u0.y;
                afr[2] = (__bf16)u0.z; afr[3] = (__bf16)u0.w;
                afr[4] = (__bf16)u1.x; afr[5] = (__bf16)u1.y;
                afr[6] = (__bf16)u1.z; afr[7] = (__bf16)u1.w;
            }
            // distribute mask to C-row owners (tile-local row i held by lane 16+i)
            #pragma unroll
            for (int r = 0; r < 4; ++r)
                mk[r] = __shfl(maskv, 16 + kh * 4 + r);
            // per-wave mask sum -> sDp[wv]
            {
                float s = (kh == 1) ? maskv : 0.f;
                s += __shfl_xor(s, 1);  s += __shfl_xor(s, 2);
                s += __shfl_xor(s, 4);  s += __shfl_xor(s, 8);
                s += __shfl_xor(s, 16); s += __shfl_xor(s, 32);
                if (lane == 0) sDp[wv] = s;
            }
            if (kh == 1) sMask[rowbase + l15] = maskv;

            f32x4 acc[8];
            #pragma unroll
            for (int nt = 0; nt < 8; ++nt) acc[nt] = f32x4{0.f, 0.f, 0.f, 0.f};
            #pragma unroll
            for (int nt = 0; nt < 8; ++nt) {
                int col = nt * 16 + l15;
                bf16x8 bfr = *(const bf16x8*)&sW1[col * 16 + (((kh & 1) * 8) ^ ((col & 1) << 3))];
                acc[nt] = __builtin_amdgcn_mfma_f32_16x16x32_bf16(afr, bfr, acc[nt], 0, 0, 0);
            }
            #pragma unroll
            for (int nt = 0; nt < 8; ++nt) {
                int col = nt * 16 + l15;
                float bb = sB1[col];
                #pragma unroll
                for (int r = 0; r < 4; ++r) {
                    float hv = fmaxf(acc[nt][r] + bb, 0.f);
                    sH[swz(rowbase + kh * 4 + r, col)] = (__bf16)hv;
                }
            }
        }

        // ============ L2 (wave-local) ============
        {
            f32x4 acc[8];
            #pragma unroll
            for (int nt = 0; nt < 8; ++nt) acc[nt] = f32x4{0.f, 0.f, 0.f, 0.f};
            #pragma unroll
            for (int kk = 0; kk < 4; ++kk) {
                int kb = kk * 32 + kh * 8;
                int arow = rowbase + l15;
                bf16x8 a = *(const bf16x8*)&sH[arow * 128 + (kb ^ ((arow & 7) << 3))];
                #pragma unroll
                for (int nt = 0; nt < 8; ++nt) {
                    int col = nt * 16 + l15;
                    bf16x8 b = *(const bf16x8*)&sW2[col * 128 + (kb ^ ((col & 7) << 3))];
                    acc[nt] = __builtin_amdgcn_mfma_f32_16x16x32_bf16(a, b, acc[nt], 0, 0, 0);
                }
            }
            #pragma unroll
            for (int nt = 0; nt < 8; ++nt) {
                int col = nt * 16 + l15;
                float bb = sB2[col];
                #pragma unroll
                for (int r = 0; r < 4; ++r) {
                    float hv = fmaxf(acc[nt][r] + bb, 0.f);
                    sH[swz(rowbase + kh * 4 + r, col)] = (__bf16)hv;   // h2 over h1 (own rows)
                }
            }
        }

        // ============ L3 (wave-local) + colsum ============
        {
            f32x4 acc[8];
            #pragma unroll
            for (int nt = 0; nt < 8; ++nt) acc[nt] = f32x4{0.f, 0.f, 0.f, 0.f};
            #pragma unroll
            for (int kk = 0; kk < 4; ++kk) {
                int kb = kk * 32 + kh * 8;
                int arow = rowbase + l15;
                bf16x8 a = *(const bf16x8*)&sH[arow * 128 + (kb ^ ((arow & 7) << 3))];
                #pragma unroll
                for (int nt = 0; nt < 8; ++nt) {
                    int col = nt * 16 + l15;
                    bf16x8 b = *(const bf16x8*)&sW3[col * 128 + (kb ^ ((col & 7) << 3))];
                    acc[nt] = __builtin_amdgcn_mfma_f32_16x16x32_bf16(a, b, acc[nt], 0, 0, 0);
                }
            }
            float cs[8];
            #pragma unroll
            for (int nt = 0; nt < 8; ++nt) cs[nt] = 0.f;
            #pragma unroll
            for (int nt = 0; nt < 8; ++nt) {
                int col = nt * 16 + l15;
                float bb = sB3[col];
                #pragma unroll
                for (int r = 0; r < 4; ++r) {
                    float hv = (acc[nt][r] + bb) * mk[r];
                    cs[nt] += hv;
                    sXr[swz(rowbase + kh * 4 + r, col)] = (__bf16)hv;
                }
            }
            #pragma unroll
            for (int nt = 0; nt < 8; ++nt) {
                float c = cs[nt];
                c += __shfl_xor(c, 16);
                c += __shfl_xor(c, 32);
                if (kh == 0) sQp[wv * 128 + nt * 16 + l15] = c;
            }
        }
        __syncthreads();

        // ============ G: v = M @ (query/den), M streamed from global ============
        {
            const int wr = wv >> 1, wc = wv & 1;
            float mreg[2][4][4];
            #pragma unroll
            for (int mt = 0; mt < 2; ++mt)
                #pragma unroll
                for (int nt = 0; nt < 4; ++nt) {
                    int d = wr * 32 + mt * 16 + kh * 4;
                    int f = wc * 64 + nt * 16 + l15;
                    #pragma unroll
                    for (int r = 0; r < 4; ++r)
                        mreg[mt][nt][r] = gM[(d + r) * 128 + f];
                }
            #pragma unroll
            for (int b = 0; b < 4; ++b) {
                float rd = 1.f / (sDp[2 * b] + sDp[2 * b + 1] + 1e-5f);
                float qv[4];
                #pragma unroll
                for (int nt = 0; nt < 4; ++nt) {
                    int f = wc * 64 + nt * 16 + l15;
                    qv[nt] = (sQp[(2 * b) * 128 + f] + sQp[(2 * b + 1) * 128 + f]) * rd;
                }
                #pragma unroll
                for (int mt = 0; mt < 2; ++mt)
                    #pragma unroll
                    for (int r = 0; r < 4; ++r) {
                        float p = mreg[mt][0][r] * qv[0] + mreg[mt][1][r] * qv[1]
                                + mreg[mt][2][r] * qv[2] + mreg[mt][3][r] * qv[3];
                        p += __shfl_xor(p, 1);
                        p += __shfl_xor(p, 2);
                        p += __shfl_xor(p, 4);
                        p += __shfl_xor(p, 8);
                        if (l15 == 0)
                            sVp[wc * 512 + b * 128 + wr * 32 + mt * 16 + kh * 4 + r] = p;
                    }
            }
        }
        __syncthreads();

        // ============ H: logits+softmax (tid<128) || aux passthrough ============
        if (tid < 128) {
            int m = tid, b = m >> 5;
            float a = 0.f;
            #pragma unroll
            for (int c8 = 0; c8 < 16; ++c8) {
                bf16x8 xv = *(const bf16x8*)&sXr[m * 128 + ((c8 * 8) ^ ((m & 7) << 3))];
                f32x4 v0 = *(const f32x4*)&sVp[b * 128 + c8 * 8];
                f32x4 v1 = *(const f32x4*)&sVp[b * 128 + c8 * 8 + 4];
                f32x4 w0 = *(const f32x4*)&sVp[512 + b * 128 + c8 * 8];
                f32x4 w1 = *(const f32x4*)&sVp[512 + b * 128 + c8 * 8 + 4];
                a += (float)xv[0] * (v0.x + w0.x) + (float)xv[1] * (v0.y + w0.y)
                   + (float)xv[2] * (v0.z + w0.z) + (float)xv[3] * (v0.w + w0.w)
                   + (float)xv[4] * (v1.x + w1.x) + (float)xv[5] * (v1.y + w1.y)
                   + (float)xv[6] * (v1.z + w1.z) + (float)xv[7] * (v1.w + w1.w);
            }
            float logit = a + (1.0f - sMask[m]) * (-1e9f);
            float mx = logit;
            #pragma unroll
            for (int off = 16; off > 0; off >>= 1) mx = fmaxf(mx, __shfl_xor(mx, off, 32));
            float ex = __expf(logit - mx);
            float sm = ex;
            #pragma unroll
            for (int off = 16; off > 0; off >>= 1) sm += __shfl_xor(sm, off, 32);
            sWgt[m] = ex / sm;
        } else if (tid < 384) {
            int t = tid - 128;
            int r = t >> 6, j = t & 63;
            out[(row0 + r) * 192 + j] = (j < 32) ? obs[(size_t)(row0 + r) * 576 + j]
                                                 : obs[(size_t)(row0 + r) * 576 + 512 + j];
        }
        __syncthreads();

        // ============ I: out_att[e] = sum_n w[n] * x_real[n][e] ============
        {
            int r = tid >> 7, e = tid & 127;
            float a = 0.f;
            #pragma unroll 8
            for (int i = 0; i < 32; ++i)
                a += sWgt[r * 32 + i] * (float)sXr[swz(r * 32 + i, e)];
            out[(row0 + r) * 192 + 64 + e] = a;
        }
        __syncthreads();   // protect LDS reuse next iteration
    }
}

extern "C" void kernel_launch(void* const* d_in, const int* in_sizes, int n_in,
                              void* d_out, int out_size, void* d_ws, size_t ws_size,
                              hipStream_t stream) {
    const float* obs = (const float*)d_in[0];
    const float* W1  = (const float*)d_in[1];
    const float* b1  = (const float*)d_in[2];
    const float* W2  = (const float*)d_in[3];
    const float* b2  = (const float*)d_in[4];
    const float* W3  = (const float*)d_in[5];
    const float* b3  = (const float*)d_in[6];
    const float* Uq  = (const float*)d_in[7];
    const float* Ur  = (const float*)d_in[8];
    float* out = (float*)d_out;
    unsigned char* ws = (unsigned char*)d_ws;

    pack_kernel<<<dim3(128), dim3(128), 0, stream>>>(W1, W2, W3, Uq, Ur, ws);
    fused_attn_kernel<<<dim3(GRID), dim3(BLOCK), 0, stream>>>(
        obs, b1, b2, b3, ws, out);
}